// Round 8
// baseline (158.972 us; speedup 1.0000x reference)
//
#include <hip/hip_runtime.h>
#include <math.h>

// SoftCodebook fused kernel v10 for MI355X (gfx950).
// p = softmax( (h/||h||) @ (proto/||proto||)^T / 0.1 ),  z = p @ proto
// v10 = v9 (vectorized output path via wave-private LDS staging, z-image
// bank-conflict XOR fix) + explicit compiler memory fences around every
// LDS staging hand-off. v9's index algebra verifies by hand; its failure
// mode is TBAA-based reordering across type-punned LDS accesses (_Float16
// pbuf vs float staging writes vs f32x4 readbacks are distinct TBAA tags ->
// clang may hoist readbacks over writes / sink pbuf writes below the
// staging clobber). asm volatile("" ::: "memory") emits no instructions;
// it only pins program order at IR level. DS pipe is in-order per wave.

#define EPS 1e-12f
#define TAU_INV 10.0f

typedef _Float16 f16x8 __attribute__((ext_vector_type(8)));
typedef float f32x4 __attribute__((ext_vector_type(4)));

#define PB_STRIDE 136   // halves per pbuf row: 272 B = 17*16 (16B-aligned rows)
#define CFENCE() asm volatile("" ::: "memory")

// ---------------------------------------------------------------------------
// k_main: 1024 threads = 16 waves, each owns 16 rows; grid = M/256 = 256.
__global__ __launch_bounds__(1024, 4) void k_main(
    const float* __restrict__ h,
    const float* __restrict__ proto,    // (K=128, D=256) fp32
    float* __restrict__ out_p,
    float* __restrict__ out_z) {

    // halves: simB [0,32768) | zB [32768,65536) | tail [65536,68096)
    __shared__ _Float16 lds[68096];     // 136192 B
    __shared__ float norms[128];        // prototype L2 norms

    const int tid = threadIdx.x;
    const int w = tid >> 6;             // 0..15
    const int lane = tid & 63;
    const int m = lane & 15;
    const int quad = lane >> 4;
    const int row0 = blockIdx.x * 256 + w * 16;

    // --- h burst first (HBM latency hides under the LDS build phase)
    const float* hrow = h + (size_t)(row0 + m) * 256 + quad * 8;
    float4 hv[16];
    #pragma unroll
    for (int c = 0; c < 8; c++) {
        hv[c * 2 + 0] = *(const float4*)(hrow + c * 32);
        hv[c * 2 + 1] = *(const float4*)(hrow + c * 32 + 4);
    }

    // =======================================================================
    // In-LDS codebook build. Wave w owns protos kp = 8w .. 8w+7;
    // 8 lanes per proto, each lane owns 32 d-values: d = (lane&7)*32 + 0..31.
    {
        const int kp = w * 8 + (lane >> 3);
        const int l8 = lane & 7;
        const float* psrc = proto + (size_t)kp * 256 + l8 * 32;
        float4 pv[8];
        #pragma unroll
        for (int i = 0; i < 8; i++) pv[i] = *(const float4*)(psrc + i * 4);

        float ss = 0.f;
        #pragma unroll
        for (int i = 0; i < 8; i++) {
            ss += pv[i].x * pv[i].x + pv[i].y * pv[i].y
                + pv[i].z * pv[i].z + pv[i].w * pv[i].w;
        }
        ss += __shfl_xor(ss, 1, 64);
        ss += __shfl_xor(ss, 2, 64);
        ss += __shfl_xor(ss, 4, 64);
        const float nrm = fmaxf(sqrtf(ss), EPS);      // proto = cbar * nrm
        const float inv = 1.0f / nrm;
        if (l8 == 0) norms[kp] = nrm;

        _Float16 cb[32];
        #pragma unroll
        for (int i = 0; i < 8; i++) {
            cb[i*4+0] = (_Float16)(pv[i].x * inv);
            cb[i*4+1] = (_Float16)(pv[i].y * inv);
            cb[i*4+2] = (_Float16)(pv[i].z * inv);
            cb[i*4+3] = (_Float16)(pv[i].w * inv);
        }

        // sim image: simB[(t*8+c)*512 + (q*16+mm)*8 + j] = cbar[kp][c*32+q*8+j]
        {
            const int t = kp >> 4, mm = kp & 15;
            _Float16* base = lds + (t * 8 + l8) * 512 + mm * 8;
            #pragma unroll
            for (int q = 0; q < 4; q++)
                *(f16x8*)(base + q * 128) = *(const f16x8*)&cb[q * 8];
        }

        // z image (dt-XOR swizzled to kill the 32-way bank conflict):
        //   zB[(dt*4+kc)*512 + qz*128 + ((mz*8) ^ ((dt&7)<<3)) + jz]
        //     = cbar[kp][dt*16+mz]
        {
            const int kc = kp >> 5, qz = (kp >> 3) & 3, jz = kp & 7;
            _Float16* zb = lds + 32768 + kc * 512 + qz * 128 + jz;
            #pragma unroll
            for (int dd = 0; dd < 32; dd++) {
                const int dt = l8 * 2 + (dd >> 4);
                const int mz = dd & 15;
                zb[(size_t)dt * 2048 + ((mz * 8) ^ ((dt & 7) << 3))] = cb[dd];
            }
        }
    }

    // --- h sumsq + f16 convert (overlaps proto/h load latency)
    float s = 0.f;
    #pragma unroll
    for (int i = 0; i < 16; i++) {
        s += hv[i].x * hv[i].x + hv[i].y * hv[i].y
           + hv[i].z * hv[i].z + hv[i].w * hv[i].w;
    }
    f16x8 A[8];
    #pragma unroll
    for (int c = 0; c < 8; c++) {
        A[c][0] = (_Float16)hv[c*2+0].x; A[c][1] = (_Float16)hv[c*2+0].y;
        A[c][2] = (_Float16)hv[c*2+0].z; A[c][3] = (_Float16)hv[c*2+0].w;
        A[c][4] = (_Float16)hv[c*2+1].x; A[c][5] = (_Float16)hv[c*2+1].y;
        A[c][6] = (_Float16)hv[c*2+1].z; A[c][7] = (_Float16)hv[c*2+1].w;
    }
    s += __shfl_xor(s, 16, 64);
    s += __shfl_xor(s, 32, 64);
    const float inv = 1.0f / fmaxf(sqrtf(s), EPS);   // 1/||h[row m]||

    // softmax slope per output row r; log2e folded in: p = exp2((sim-mx)*tinv)
    float tinv[4];
    #pragma unroll
    for (int r = 0; r < 4; r++)
        tinv[r] = TAU_INV * 1.44269504f * __shfl(inv, quad * 4 + r, 64);

    __syncthreads();    // codebook images + norms resident

    // --- sim GEMM from LDS: acc[t][row r] = h[row]·cbar[t*16+m]
    const _Float16* sBl = lds;
    f32x4 acc[8] = {};
    #pragma unroll
    for (int t = 0; t < 8; t++) {
        f16x8 Bt[8];
        #pragma unroll
        for (int c = 0; c < 8; c++)
            Bt[c] = *(const f16x8*)&sBl[(t * 8 + c) * 512 + lane * 8];
        #pragma unroll
        for (int c = 0; c < 8; c++)
            acc[t] = __builtin_amdgcn_mfma_f32_16x16x32_f16(A[c], Bt[c], acc[t], 0, 0, 0);
    }

    // prototype scales for the z-path A operand (proto = cbar * norm), from LDS
    float sc_l[8];
    #pragma unroll
    for (int t = 0; t < 8; t++) sc_l[t] = norms[t * 16 + m];

    __syncthreads();    // ALL sim reads done -> pbuf/staging may overlay simB

    // wave-private slot (4352 B): pbuf f16 now, f32 staging chunks later
    _Float16* pb = lds + (w == 15 ? 65536 : w * (16 * PB_STRIDE));
    char* slot = (char*)pb;

    // --- softmax over K=128 per row; p kept in acc (f32), p*scale -> pbuf f16
    #pragma unroll
    for (int r = 0; r < 4; r++) {
        float mx = acc[0][r];
        #pragma unroll
        for (int t = 1; t < 8; t++) mx = fmaxf(mx, acc[t][r]);
        #pragma unroll
        for (int msk = 1; msk < 16; msk <<= 1) mx = fmaxf(mx, __shfl_xor(mx, msk, 64));
        float e[8];
        float sum = 0.f;
        #pragma unroll
        for (int t = 0; t < 8; t++) {
            e[t] = __builtin_amdgcn_exp2f((acc[t][r] - mx) * tinv[r]);
            sum += e[t];
        }
        #pragma unroll
        for (int msk = 1; msk < 16; msk <<= 1) sum += __shfl_xor(sum, msk, 64);
        const float rs = 1.0f / sum;
        const int prow = quad * 4 + r;
        #pragma unroll
        for (int t = 0; t < 8; t++) {
            const float p = e[t] * rs;
            acc[t][r] = p;                                   // keep p in regs
            pb[prow * PB_STRIDE + t * 16 + m] = (_Float16)(p * sc_l[t]);
        }
    }

    CFENCE();   // pbuf f16 writes ordered before Ap reads

    // --- load z-path A fragments BEFORE the slot is reused for staging
    f16x8 Ap[4];
    #pragma unroll
    for (int kc = 0; kc < 4; kc++)
        Ap[kc] = *(const f16x8*)&pb[m * PB_STRIDE + kc * 32 + quad * 8];

    CFENCE();   // Ap reads ordered before the slot is clobbered

    // --- p: stage 2 chunks of [16 rows][64 cols] f32 in slot, store dwordx4
    #pragma unroll
    for (int ch = 0; ch < 2; ch++) {
        #pragma unroll
        for (int r = 0; r < 4; r++) {
            const int row = quad * 4 + r;
            const int sw = (row & 12) << 4;
            #pragma unroll
            for (int tt = 0; tt < 4; tt++)
                *(float*)(slot + row * 256 + ((tt * 64 + m * 4) ^ sw)) =
                    acc[ch * 4 + tt][r];
        }
        CFENCE();   // writes before readback
        #pragma unroll
        for (int rg = 0; rg < 4; rg++) {
            const int row = rg * 4 + quad;
            const int sw = (row & 12) << 4;
            const f32x4 v = *(const f32x4*)(slot + row * 256 + ((m * 16) ^ sw));
            *(f32x4*)(out_p + (size_t)(row0 + row) * 128 + ch * 64 + m * 4) = v;
        }
        CFENCE();   // readback before next chunk's writes
    }

    // --- z GEMM in 4 dt-groups; each group staged+stored as [16][64] f32
    const _Float16* zBl = lds + 32768;
    #pragma unroll
    for (int g = 0; g < 4; g++) {
        f32x4 zc[4] = {};
        #pragma unroll
        for (int i = 0; i < 4; i++) {
            const int dt = g * 4 + i;
            f16x8 Bz[4];
            #pragma unroll
            for (int kc = 0; kc < 4; kc++)
                Bz[kc] = *(const f16x8*)&zBl[(dt * 4 + kc) * 512 +
                                             ((lane * 8) ^ ((dt & 7) << 3))];
            #pragma unroll
            for (int kc = 0; kc < 4; kc++)
                zc[i] = __builtin_amdgcn_mfma_f32_16x16x32_f16(Ap[kc], Bz[kc], zc[i], 0, 0, 0);
        }
        #pragma unroll
        for (int i = 0; i < 4; i++) {
            #pragma unroll
            for (int r = 0; r < 4; r++) {
                const int row = quad * 4 + r;
                const int sw = (row & 12) << 4;
                *(float*)(slot + row * 256 + ((i * 64 + m * 4) ^ sw)) = zc[i][r];
            }
        }
        CFENCE();   // writes before readback
        #pragma unroll
        for (int rg = 0; rg < 4; rg++) {
            const int row = rg * 4 + quad;
            const int sw = (row & 12) << 4;
            const f32x4 v = *(const f32x4*)(slot + row * 256 + ((m * 16) ^ sw));
            *(f32x4*)(out_z + (size_t)(row0 + row) * 256 + g * 64 + m * 4) = v;
        }
        CFENCE();   // readback before next group's writes
    }
}

// ---------------------------------------------------------------------------
extern "C" void kernel_launch(void* const* d_in, const int* in_sizes, int n_in,
                              void* d_out, int out_size, void* d_ws, size_t ws_size,
                              hipStream_t stream) {
    const float* h_in  = (const float*)d_in[0];   // (B,P,D) fp32, B*P=65536, D=256
    const float* proto = (const float*)d_in[1];   // (K,D) fp32, K=128

    const int M = in_sizes[0] / 256;              // 65536 rows

    float* out_p = (float*)d_out;                 // (M,128)
    float* out_z = out_p + (size_t)M * 128;       // (M,256)

    k_main<<<dim3(M / 256), dim3(1024), 0, stream>>>(h_in, proto, out_p, out_z);
}